// Round 15
// baseline (8461.637 us; speedup 1.0000x reference)
//
#include <hip/hip_runtime.h>
#include <hip/hip_bf16.h>

// Model config
#define Lc 2
#define Hc 1024
#define NHc 16
#define HDc 64
#define FFc 4096
#define Ec 8
#define Kc 2
#define Vc 32000
#define Sc 2048
#define EPSc 1e-5f

typedef short s16x8 __attribute__((ext_vector_type(8)));
typedef float f32x4 __attribute__((ext_vector_type(4)));
typedef unsigned short us4 __attribute__((ext_vector_type(4)));
typedef unsigned short us8 __attribute__((ext_vector_type(8)));

__device__ __forceinline__ unsigned short f2bf_r(float f) {
  unsigned u = __float_as_uint(f);
  u += 0x7FFFu + ((u >> 16) & 1u);
  return (unsigned short)(u >> 16);
}
__device__ __forceinline__ float bf2f(unsigned short h) {
  return __uint_as_float((unsigned)h << 16);
}
__device__ __forceinline__ void split2(float f, unsigned short& hi, unsigned short& lo) {
  hi = f2bf_r(f);
  lo = f2bf_r(f - bf2f(hi));
}

// ---------------- embedding ----------------
__global__ __launch_bounds__(256) void k_embed(const int* __restrict__ idx,
    const float* __restrict__ tok, const float* __restrict__ pos,
    float* __restrict__ x) {
  int t = blockIdx.x;
  int id = idx[t];
  for (int i = threadIdx.x; i < Hc; i += 256)
    x[t * Hc + i] = tok[(size_t)id * Hc + i] + pos[t * Hc + i];
}

// ---------------- layernorm: fp32 out + bf16 hi/lo planes ----------------
__global__ __launch_bounds__(256) void k_ln(const float* __restrict__ x,
    const float* __restrict__ g, const float* __restrict__ b,
    float* __restrict__ o, unsigned short* __restrict__ oh,
    unsigned short* __restrict__ ol) {
  int row = blockIdx.x;
  int tid = threadIdx.x;
  const float* xr = x + (size_t)row * Hc;
  float v[4];
  float s = 0.f;
#pragma unroll
  for (int i = 0; i < 4; i++) { v[i] = xr[tid + 256 * i]; s += v[i]; }
  __shared__ float red[256];
  red[tid] = s; __syncthreads();
  for (int st = 128; st > 0; st >>= 1) {
    if (tid < st) red[tid] += red[tid + st];
    __syncthreads();
  }
  float mu = red[0] * (1.0f / Hc);
  __syncthreads();
  float s2 = 0.f;
#pragma unroll
  for (int i = 0; i < 4; i++) { float d = v[i] - mu; s2 += d * d; }
  red[tid] = s2; __syncthreads();
  for (int st = 128; st > 0; st >>= 1) {
    if (tid < st) red[tid] += red[tid + st];
    __syncthreads();
  }
  float rs = rsqrtf(red[0] * (1.0f / Hc) + EPSc);
  float* orow = o + (size_t)row * Hc;
#pragma unroll
  for (int i = 0; i < 4; i++) {
    int c = tid + 256 * i;
    float ov = (v[i] - mu) * rs * g[c] + b[c];
    orow[c] = ov;
    unsigned short hh, ll;
    split2(ov, hh, ll);
    oh[(size_t)row * Hc + c] = hh;
    ol[(size_t)row * Hc + c] = ll;
  }
}

// ---------------- MFMA GEMM (3-product hi/lo, BK=32 for occupancy) ----------------
// C = A[M,K] @ B^T; A from bf16 hi/lo planes; B fp32, split during staging.
// acc = ah*bh + al*bh + ah*bl  (al*bl ~2^-18, dropped)
// MODE 0: dense A, C = acc (+bias)(+resid), fp32 out
// MODE 1: gather A rows via elist (expert z), gelu -> Oh/Ol bf16 planes
// MODE 2: dense A rows (off+r), atomicAdd coef*acc into C[tok]
// BT 0: B stored [N][K] (NT). BT 1: B stored [K][N] (TN, transpose-stage).
// BK=32, PAD=40 shorts (80 B: 16-B aligned for b128 DS ops; 20-bank stride ->
// 2-way conflict = free per m136): LDS 30720 B -> 5 blocks/CU = 20 waves/CU
// (round-10 counters: 55 KB LDS -> 2 blocks/CU, Occupancy 3.3%, 95% stall).
#define BMg 128
#define BNg 64
#define BKg 32
#define PAD 40

template <int MODE, int BT>
__global__ __launch_bounds__(256, 4) void k_mfma_gemm(
    const unsigned short* __restrict__ Ah, const unsigned short* __restrict__ Al,
    const float* __restrict__ Bmat,
    const float* __restrict__ bias, const float* __restrict__ resid,
    float* __restrict__ C,
    unsigned short* __restrict__ Oh, unsigned short* __restrict__ Ol,
    const int* __restrict__ elist, const float* __restrict__ ecoef,
    const int* __restrict__ counts, const int* __restrict__ offs,
    int M, int N, int K) {
  int cnt = 0, off = 0;
  if (MODE >= 1) {
    int e = blockIdx.z;
    cnt = counts[e]; off = offs[e];
    if ((int)(blockIdx.x * BMg) >= cnt) return;
    Bmat += (size_t)e * (size_t)K * N;
  }
  int m0 = blockIdx.x * BMg, n0 = blockIdx.y * BNg;
  int tid = threadIdx.x;
  int l = tid & 63, w = tid >> 6;
  int wm = (w >> 1) * 64, wn = (w & 1) * 32;
  int lr = l & 15, kg = l >> 4;

  __shared__ unsigned short Ahs[BMg][PAD];
  __shared__ unsigned short Als[BMg][PAD];
  __shared__ unsigned short Bhs[BNg][PAD];
  __shared__ unsigned short Bls[BNg][PAD];

  f32x4 acc[4][2] = {};

  // A staging: 128 rows x 32 shorts per plane; 256 thr -> 16 shorts (2 us8) each
  int sr = tid >> 1;            // 0..127 (A row)
  int sc = (tid & 1) * 16;      // A k offset (0|16)
  // B staging NT: 64 n-rows x 32 k; thread: n-row = tid>>2, k off = (tid&3)*8
  int nr = tid >> 2, kc = (tid & 3) * 8;
  // B staging TN: 32 k-rows x 64 n; thread: k-row = tid>>3, n off = (tid&7)*8
  int kr = tid >> 3, nc = (tid & 7) * 8;

  int arow;
  if (MODE == 0) arow = m0 + sr;
  else if (MODE == 1) arow = (m0 + sr < cnt) ? elist[off + m0 + sr] : -1;
  else arow = (m0 + sr < cnt) ? (off + m0 + sr) : -1;

  us8 ra[2], rl4[2];
  float4 rb[2];

  auto load_tile = [&](int k0) {
    if (arow >= 0) {
      const unsigned short* ph = Ah + (size_t)arow * K + k0 + sc;
      const unsigned short* pl = Al + (size_t)arow * K + k0 + sc;
      ra[0]  = *(const us8*)(ph);
      ra[1]  = *(const us8*)(ph + 8);
      rl4[0] = *(const us8*)(pl);
      rl4[1] = *(const us8*)(pl + 8);
    } else {
      us8 z = {0, 0, 0, 0, 0, 0, 0, 0};
      ra[0] = z; ra[1] = z; rl4[0] = z; rl4[1] = z;
    }
    const float* pb = (BT == 0)
        ? Bmat + (size_t)(n0 + nr) * K + k0 + kc
        : Bmat + (size_t)(k0 + kr) * N + n0 + nc;
    rb[0] = *(const float4*)(pb);
    rb[1] = *(const float4*)(pb + 4);
  };

  auto store_tile = [&]() {
    *(us8*)&Ahs[sr][sc + 0] = ra[0];
    *(us8*)&Ahs[sr][sc + 8] = ra[1];
    *(us8*)&Als[sr][sc + 0] = rl4[0];
    *(us8*)&Als[sr][sc + 8] = rl4[1];
    if (BT == 0) {
#pragma unroll
      for (int c = 0; c < 2; ++c) {
        float4 v = rb[c];
        us4 h4, l4;
        unsigned short th, tl;
        split2(v.x, th, tl); h4.x = th; l4.x = tl;
        split2(v.y, th, tl); h4.y = th; l4.y = tl;
        split2(v.z, th, tl); h4.z = th; l4.z = tl;
        split2(v.w, th, tl); h4.w = th; l4.w = tl;
        *(us4*)&Bhs[nr][kc + 4 * c] = h4;
        *(us4*)&Bls[nr][kc + 4 * c] = l4;
      }
    } else {
#pragma unroll
      for (int c = 0; c < 2; ++c) {
        float4 v = rb[c];
        unsigned short hh, ll;
        split2(v.x, hh, ll); Bhs[nc + 4 * c + 0][kr] = hh; Bls[nc + 4 * c + 0][kr] = ll;
        split2(v.y, hh, ll); Bhs[nc + 4 * c + 1][kr] = hh; Bls[nc + 4 * c + 1][kr] = ll;
        split2(v.z, hh, ll); Bhs[nc + 4 * c + 2][kr] = hh; Bls[nc + 4 * c + 2][kr] = ll;
        split2(v.w, hh, ll); Bhs[nc + 4 * c + 3][kr] = hh; Bls[nc + 4 * c + 3][kr] = ll;
      }
    }
  };

  load_tile(0);
  for (int k0 = 0; k0 < K; k0 += BKg) {
    store_tile();
    __syncthreads();
    if (k0 + BKg < K) load_tile(k0 + BKg);
    // ---- compute on LDS tile (one 32-wide K slab) ----
    int kk = kg * 8;
    s16x8 bh[2], bl[2];
#pragma unroll
    for (int nf = 0; nf < 2; ++nf) {
      bh[nf] = *(const s16x8*)&Bhs[wn + nf * 16 + lr][kk];
      bl[nf] = *(const s16x8*)&Bls[wn + nf * 16 + lr][kk];
    }
#pragma unroll
    for (int mf = 0; mf < 4; ++mf) {
      s16x8 ah = *(const s16x8*)&Ahs[wm + mf * 16 + lr][kk];
      s16x8 al = *(const s16x8*)&Als[wm + mf * 16 + lr][kk];
#pragma unroll
      for (int nf = 0; nf < 2; ++nf) {
        acc[mf][nf] = __builtin_amdgcn_mfma_f32_16x16x32_bf16(ah, bh[nf], acc[mf][nf], 0, 0, 0);
        acc[mf][nf] = __builtin_amdgcn_mfma_f32_16x16x32_bf16(al, bh[nf], acc[mf][nf], 0, 0, 0);
        acc[mf][nf] = __builtin_amdgcn_mfma_f32_16x16x32_bf16(ah, bl[nf], acc[mf][nf], 0, 0, 0);
      }
    }
    __syncthreads();
  }

  // ---- epilogue ----
  int rbase = (l >> 4) * 4;
#pragma unroll
  for (int mf = 0; mf < 4; ++mf) {
#pragma unroll
    for (int nf = 0; nf < 2; ++nf) {
      int n = n0 + wn + nf * 16 + lr;
#pragma unroll
      for (int j = 0; j < 4; ++j) {
        int rloc = m0 + wm + mf * 16 + rbase + j;
        float v = acc[mf][nf][j];
        if (MODE == 0) {
          if (bias) v += bias[n];
          if (resid) v += resid[(size_t)rloc * N + n];
          C[(size_t)rloc * N + n] = v;
        } else if (MODE == 1) {
          if (rloc < cnt) {
            float g = 0.5f * v * (1.0f + erff(v * 0.70710678118654752f));
            unsigned short hh, ll;
            split2(g, hh, ll);
            size_t p = (size_t)(off + rloc) * N + n;
            Oh[p] = hh; Ol[p] = ll;
          }
        } else {
          if (rloc < cnt) {
            int tok = elist[off + rloc];
            float cf = ecoef[off + rloc];
            atomicAdd(&C[(size_t)tok * N + n], cf * v);
          }
        }
      }
    }
  }
}

// ---------------- tiled flash attention (epilogue -> bf16 hi/lo ctx planes) ----------------
__global__ __launch_bounds__(256) void k_attn_tile(const float* __restrict__ qkv,
                                                   unsigned short* __restrict__ ctx_hi,
                                                   unsigned short* __restrict__ ctx_lo) {
  int qt = blockIdx.x, h = blockIdx.y;
  int q0 = qt * 64;
  int tid = threadIdx.x;
  int tx = tid & 15, ty = tid >> 4;

  __shared__ float Qs[64][68];   // Q^T: [d][q]
  __shared__ float KPs[64][68];  // K^T: [d][j], reused as P^T: [j][q]
  __shared__ float Vs[64][68];   // V:   [j][d]

  float oacc[4][4] = {};
  float m[4] = {-INFINITY, -INFINITY, -INFINITY, -INFINITY};
  float l[4] = {0.f, 0.f, 0.f, 0.f};

  int lrr = tid >> 2;
  int d0 = (tid & 3) * 16;

  {
    const float* qbase = qkv + (size_t)(q0 + lrr) * 3072 + h * 64 + d0;
#pragma unroll
    for (int c = 0; c < 4; ++c) {
      float4 qv = *(const float4*)(qbase + 4 * c);
      Qs[d0 + 4 * c + 0][lrr] = qv.x * 0.125f;
      Qs[d0 + 4 * c + 1][lrr] = qv.y * 0.125f;
      Qs[d0 + 4 * c + 2][lrr] = qv.z * 0.125f;
      Qs[d0 + 4 * c + 3][lrr] = qv.w * 0.125f;
    }
  }
  __syncthreads();

  for (int jt = 0; jt <= qt; ++jt) {
    int j0 = jt * 64;
    {
      const float* kbase = qkv + (size_t)(j0 + lrr) * 3072 + 1024 + h * 64 + d0;
      const float* vbase = qkv + (size_t)(j0 + lrr) * 3072 + 2048 + h * 64 + d0;
#pragma unroll
      for (int c = 0; c < 4; ++c) {
        float4 kv = *(const float4*)(kbase + 4 * c);
        KPs[d0 + 4 * c + 0][lrr] = kv.x;
        KPs[d0 + 4 * c + 1][lrr] = kv.y;
        KPs[d0 + 4 * c + 2][lrr] = kv.z;
        KPs[d0 + 4 * c + 3][lrr] = kv.w;
        *(float4*)&Vs[lrr][d0 + 4 * c] = *(const float4*)(vbase + 4 * c);
      }
    }
    __syncthreads();

    float sacc[4][4] = {};
#pragma unroll 8
    for (int kk = 0; kk < 64; ++kk) {
      float4 a = *(const float4*)&Qs[kk][ty * 4];
      float4 b = *(const float4*)&KPs[kk][tx * 4];
      const float* ap = (const float*)&a;
      const float* bp = (const float*)&b;
#pragma unroll
      for (int i = 0; i < 4; ++i)
#pragma unroll
        for (int jj = 0; jj < 4; ++jj)
          sacc[i][jj] = fmaf(ap[i], bp[jj], sacc[i][jj]);
    }

    if (jt == qt) {
#pragma unroll
      for (int i = 0; i < 4; ++i)
#pragma unroll
        for (int jj = 0; jj < 4; ++jj)
          if (tx * 4 + jj > ty * 4 + i) sacc[i][jj] = -INFINITY;
    }

#pragma unroll
    for (int i = 0; i < 4; ++i) {
      float rm = fmaxf(fmaxf(sacc[i][0], sacc[i][1]),
                       fmaxf(sacc[i][2], sacc[i][3]));
#pragma unroll
      for (int o = 8; o > 0; o >>= 1) rm = fmaxf(rm, __shfl_xor(rm, o, 64));
      float mnew = fmaxf(m[i], rm);
      float alpha = __expf(m[i] - mnew);
      float rs = 0.f;
#pragma unroll
      for (int jj = 0; jj < 4; ++jj) {
        float p = __expf(sacc[i][jj] - mnew);
        sacc[i][jj] = p;
        rs += p;
      }
#pragma unroll
      for (int o = 8; o > 0; o >>= 1) rs += __shfl_xor(rs, o, 64);
      l[i] = l[i] * alpha + rs;
      m[i] = mnew;
#pragma unroll
      for (int jj = 0; jj < 4; ++jj) oacc[i][jj] *= alpha;
    }

    __syncthreads();
#pragma unroll
    for (int i = 0; i < 4; ++i)
#pragma unroll
      for (int jj = 0; jj < 4; ++jj)
        KPs[tx * 4 + jj][ty * 4 + i] = sacc[i][jj];
    __syncthreads();

#pragma unroll 8
    for (int kk = 0; kk < 64; ++kk) {
      float4 a = *(const float4*)&KPs[kk][ty * 4];
      float4 b = *(const float4*)&Vs[kk][tx * 4];
      const float* ap = (const float*)&a;
      const float* bp = (const float*)&b;
#pragma unroll
      for (int i = 0; i < 4; ++i)
#pragma unroll
        for (int jj = 0; jj < 4; ++jj)
          oacc[i][jj] = fmaf(ap[i], bp[jj], oacc[i][jj]);
    }
    __syncthreads();
  }

#pragma unroll
  for (int i = 0; i < 4; ++i) {
    float inv = 1.0f / l[i];
    int mrow = q0 + ty * 4 + i;
    size_t base = (size_t)mrow * Hc + h * 64 + tx * 4;
    us4 hv, lv;
#pragma unroll
    for (int jj = 0; jj < 4; ++jj) {
      float v = oacc[i][jj] * inv;
      unsigned short hh, ll;
      split2(v, hh, ll);
      hv[jj] = hh; lv[jj] = ll;
    }
    *(us4*)&ctx_hi[base] = hv;
    *(us4*)&ctx_lo[base] = lv;
  }
}

// ---------------- router: softmax over 8 experts + top-2 + counts ----------------
__global__ __launch_bounds__(256) void k_router(const float* __restrict__ xf,
    const float* __restrict__ rw, int* __restrict__ topi,
    float* __restrict__ topw, int* __restrict__ counts) {
  int t = blockIdx.x;
  int tid = threadIdx.x;
  int e = tid >> 5, l = tid & 31;
  const float* xr = xf + (size_t)t * Hc;
  const float* we = rw + (size_t)e * Hc;
  float s = 0.f;
  for (int hh = l; hh < Hc; hh += 32) s += xr[hh] * we[hh];
  __shared__ float red[256];
  red[tid] = s; __syncthreads();
  for (int st = 16; st > 0; st >>= 1) {
    if (l < st) red[tid] += red[tid + st];
    __syncthreads();
  }
  if (tid == 0) {
    float lg[Ec], pr[Ec];
    float mx = -INFINITY;
    for (int k = 0; k < Ec; k++) { lg[k] = red[k * 32]; mx = fmaxf(mx, lg[k]); }
    float ps = 0.f;
    for (int k = 0; k < Ec; k++) { pr[k] = expf(lg[k] - mx); ps += pr[k]; }
    float inv = 1.0f / ps;
    for (int k = 0; k < Ec; k++) pr[k] *= inv;
    int i1 = 0;
    for (int k = 1; k < Ec; k++) if (pr[k] > pr[i1]) i1 = k;
    int i2 = (i1 == 0) ? 1 : 0;
    for (int k = 0; k < Ec; k++)
      if (k != i1 && pr[k] > pr[i2]) i2 = k;
    topi[2 * t] = i1; topi[2 * t + 1] = i2;
    topw[2 * t] = pr[i1]; topw[2 * t + 1] = pr[i2];
    atomicAdd(&counts[i1], 1);
    atomicAdd(&counts[i2], 1);
  }
}

__global__ void k_offs(const int* __restrict__ counts, int* __restrict__ offs) {
  int acc = 0;
  for (int e = 0; e < Ec; e++) { offs[e] = acc; acc += counts[e]; }
}

__global__ __launch_bounds__(256) void k_scatter(const int* __restrict__ topi,
    const float* __restrict__ topw, const int* __restrict__ offs,
    int* __restrict__ cursor, int* __restrict__ elist,
    float* __restrict__ ecoef) {
  int t = blockIdx.x * 256 + threadIdx.x;
  if (t >= Sc) return;
#pragma unroll
  for (int s = 0; s < Kc; s++) {
    int e = topi[2 * t + s];
    int p = atomicAdd(&cursor[e], 1);
    int gslot = offs[e] + p;
    elist[gslot] = t;
    ecoef[gslot] = topw[2 * t + s];
  }
}

extern "C" void kernel_launch(void* const* d_in, const int* in_sizes, int n_in,
                              void* d_out, int out_size, void* d_ws, size_t ws_size,
                              hipStream_t stream) {
  const int*   idx   = (const int*)d_in[0];
  const float* tok   = (const float*)d_in[1];
  const float* pos   = (const float*)d_in[2];
  const float* ln1g  = (const float*)d_in[3];
  const float* ln1b  = (const float*)d_in[4];
  const float* wqkv  = (const float*)d_in[5];
  const float* bqkv  = (const float*)d_in[6];
  const float* wo    = (const float*)d_in[7];
  const float* bo    = (const float*)d_in[8];
  const float* ln2g  = (const float*)d_in[9];
  const float* ln2b  = (const float*)d_in[10];
  const float* rw    = (const float*)d_in[11];
  const float* w1    = (const float*)d_in[12];
  const float* w2    = (const float*)d_in[13];
  const float* lnfg  = (const float*)d_in[14];
  const float* lnfb  = (const float*)d_in[15];

  float* ws   = (float*)d_ws;
  float* x    = ws;                    // Sc*Hc
  float* lnb  = x + Sc * Hc;           // Sc*Hc
  float* qkv  = lnb + Sc * Hc;         // Sc*3*Hc
  float* topw  = qkv + Sc * 3 * Hc;    // Sc*Kc
  float* ecoef = topw + Sc * Kc;       // Sc*Kc
  int* topi    = (int*)(ecoef + Sc * Kc);  // Sc*Kc
  int* elist   = topi + Sc * Kc;           // Sc*Kc
  int* counts  = elist + Sc * Kc;          // Ec
  int* cursor  = counts + Ec;              // Ec
  int* offs    = cursor + Ec;              // Ec
  unsigned short* lnb_hi = (unsigned short*)(offs + Ec);   // Sc*Hc ushort
  unsigned short* lnb_lo = lnb_hi + (size_t)Sc * Hc;       // Sc*Hc ushort

  // d_out scratch (262 MB): h1 bf16 planes + ctx bf16 planes; all consumed
  // before the LM head overwrites d_out with logits.
  unsigned short* h1_hi  = (unsigned short*)d_out;                 // Sc*Kc*FFc
  unsigned short* h1_lo  = h1_hi + (size_t)Sc * Kc * FFc;
  unsigned short* ctx_hi = h1_lo + (size_t)Sc * Kc * FFc;          // Sc*Hc
  unsigned short* ctx_lo = ctx_hi + (size_t)Sc * Hc;

  k_embed<<<Sc, 256, 0, stream>>>(idx, tok, pos, x);
  for (int l = 0; l < Lc; l++) {
    k_ln<<<Sc, 256, 0, stream>>>(x, ln1g + l * Hc, ln1b + l * Hc, lnb, lnb_hi, lnb_lo);
    // QKV: [S,3H] = lnb @ wqkv^T + bqkv
    k_mfma_gemm<0, 0><<<dim3(Sc / BMg, 3 * Hc / BNg), 256, 0, stream>>>(
        lnb_hi, lnb_lo, wqkv + (size_t)l * 3 * Hc * Hc, bqkv + l * 3 * Hc,
        nullptr, qkv, nullptr, nullptr, nullptr, nullptr, nullptr, nullptr,
        Sc, 3 * Hc, Hc);
    k_attn_tile<<<dim3(Sc / 64, NHc), 256, 0, stream>>>(qkv, ctx_hi, ctx_lo);
    // WO: x += ctx @ wo^T + bo
    k_mfma_gemm<0, 0><<<dim3(Sc / BMg, Hc / BNg), 256, 0, stream>>>(
        ctx_hi, ctx_lo, wo + (size_t)l * Hc * Hc, bo + l * Hc, x, x,
        nullptr, nullptr, nullptr, nullptr, nullptr, nullptr, Sc, Hc, Hc);
    k_ln<<<Sc, 256, 0, stream>>>(x, ln2g + l * Hc, ln2b + l * Hc, lnb, lnb_hi, lnb_lo);
    hipMemsetAsync(counts, 0, 2 * Ec * sizeof(int), stream);
    k_router<<<Sc, 256, 0, stream>>>(lnb, rw + (size_t)l * Ec * Hc, topi, topw, counts);
    k_offs<<<1, 1, 0, stream>>>(counts, offs);
    k_scatter<<<Sc / 256, 256, 0, stream>>>(topi, topw, offs, cursor, elist, ecoef);
    // MoE GEMM1: h1 = gelu(gather(lnb) @ w1[e]); w1 is [K=H][N=FF]
    k_mfma_gemm<1, 1><<<dim3(Sc * Kc / BMg, FFc / BNg, Ec), 256, 0, stream>>>(
        lnb_hi, lnb_lo, w1 + (size_t)l * Ec * Hc * FFc, nullptr, nullptr,
        nullptr, h1_hi, h1_lo, elist, nullptr, counts, offs, Sc * Kc, FFc, Hc);
    // MoE GEMM2: x[tok] += coef * (h1 @ w2[e]); w2 is [K=FF][N=H]
    k_mfma_gemm<2, 1><<<dim3(Sc * Kc / BMg, Hc / BNg, Ec), 256, 0, stream>>>(
        h1_hi, h1_lo, w2 + (size_t)l * Ec * FFc * Hc, nullptr, nullptr,
        x, nullptr, nullptr, elist, ecoef, counts, offs, Sc * Kc, Hc, FFc);
  }
  k_ln<<<Sc, 256, 0, stream>>>(x, lnfg, lnfb, lnb, lnb_hi, lnb_lo);
  // LM head: logits = lnb @ tok^T
  k_mfma_gemm<0, 0><<<dim3(Sc / BMg, Vc / BNg), 256, 0, stream>>>(
      lnb_hi, lnb_lo, tok, nullptr, nullptr, (float*)d_out,
      nullptr, nullptr, nullptr, nullptr, nullptr, nullptr, Sc, Vc, Hc);
}

// Round 16
// 3587.359 us; speedup vs baseline: 2.3587x; 2.3587x over previous
//
#include <hip/hip_runtime.h>
#include <hip/hip_bf16.h>

// Model config
#define Lc 2
#define Hc 1024
#define NHc 16
#define HDc 64
#define FFc 4096
#define Ec 8
#define Kc 2
#define Vc 32000
#define Sc 2048
#define EPSc 1e-5f

typedef short s16x8 __attribute__((ext_vector_type(8)));
typedef float f32x4 __attribute__((ext_vector_type(4)));
typedef unsigned short us4 __attribute__((ext_vector_type(4)));
typedef unsigned short us8 __attribute__((ext_vector_type(8)));

__device__ __forceinline__ unsigned short f2bf_r(float f) {
  unsigned u = __float_as_uint(f);
  u += 0x7FFFu + ((u >> 16) & 1u);
  return (unsigned short)(u >> 16);
}
__device__ __forceinline__ float bf2f(unsigned short h) {
  return __uint_as_float((unsigned)h << 16);
}
__device__ __forceinline__ void split2(float f, unsigned short& hi, unsigned short& lo) {
  hi = f2bf_r(f);
  lo = f2bf_r(f - bf2f(hi));
}

// ---------------- embedding ----------------
__global__ __launch_bounds__(256) void k_embed(const int* __restrict__ idx,
    const float* __restrict__ tok, const float* __restrict__ pos,
    float* __restrict__ x) {
  int t = blockIdx.x;
  int id = idx[t];
  for (int i = threadIdx.x; i < Hc; i += 256)
    x[t * Hc + i] = tok[(size_t)id * Hc + i] + pos[t * Hc + i];
}

// ---------------- layernorm: fp32 out + bf16 hi/lo planes ----------------
__global__ __launch_bounds__(256) void k_ln(const float* __restrict__ x,
    const float* __restrict__ g, const float* __restrict__ b,
    float* __restrict__ o, unsigned short* __restrict__ oh,
    unsigned short* __restrict__ ol) {
  int row = blockIdx.x;
  int tid = threadIdx.x;
  const float* xr = x + (size_t)row * Hc;
  float v[4];
  float s = 0.f;
#pragma unroll
  for (int i = 0; i < 4; i++) { v[i] = xr[tid + 256 * i]; s += v[i]; }
  __shared__ float red[256];
  red[tid] = s; __syncthreads();
  for (int st = 128; st > 0; st >>= 1) {
    if (tid < st) red[tid] += red[tid + st];
    __syncthreads();
  }
  float mu = red[0] * (1.0f / Hc);
  __syncthreads();
  float s2 = 0.f;
#pragma unroll
  for (int i = 0; i < 4; i++) { float d = v[i] - mu; s2 += d * d; }
  red[tid] = s2; __syncthreads();
  for (int st = 128; st > 0; st >>= 1) {
    if (tid < st) red[tid] += red[tid + st];
    __syncthreads();
  }
  float rs = rsqrtf(red[0] * (1.0f / Hc) + EPSc);
  float* orow = o + (size_t)row * Hc;
#pragma unroll
  for (int i = 0; i < 4; i++) {
    int c = tid + 256 * i;
    float ov = (v[i] - mu) * rs * g[c] + b[c];
    orow[c] = ov;
    unsigned short hh, ll;
    split2(ov, hh, ll);
    oh[(size_t)row * Hc + c] = hh;
    ol[(size_t)row * Hc + c] = ll;
  }
}

// ---------------- MFMA GEMM (3-product hi/lo, BK=32) ----------------
// C = A[M,K] @ B^T; A from bf16 hi/lo planes; B fp32, split during staging.
// acc = ah*bh + al*bh + ah*bl  (al*bl ~2^-18, dropped)
// MODE 0: dense A, C = acc (+bias)(+resid), fp32 out. 2D grid (all active).
// MODE 1: gather A rows via elist, gelu -> Oh/Ol bf16 planes. 1D grid.
// MODE 2: dense A rows (off+r), atomicAdd coef*acc into C[tok]. 1D grid.
// MoE 1D grid decode: id = nb + NBn*(mb + NBm*e), n fastest. Round-15 counters
// showed the old (m,n,e) grid put ALL active blocks (m<4 of 32) on XCDs 0-3
// (id%8 = m), idling half the chip: Occupancy 6.2%, MoE dispatch 1540us.
// BT 0: B stored [N][K] (NT). BT 1: B stored [K][N] (TN, transpose-stage).
#define BMg 128
#define BNg 64
#define BKg 32
#define PAD 40

template <int MODE, int BT>
__global__ __launch_bounds__(256, 4) void k_mfma_gemm(
    const unsigned short* __restrict__ Ah, const unsigned short* __restrict__ Al,
    const float* __restrict__ Bmat,
    const float* __restrict__ bias, const float* __restrict__ resid,
    float* __restrict__ C,
    unsigned short* __restrict__ Oh, unsigned short* __restrict__ Ol,
    const int* __restrict__ elist, const float* __restrict__ ecoef,
    const int* __restrict__ counts, const int* __restrict__ offs,
    int M, int N, int K) {
  int cnt = 0, off = 0;
  int m0, n0;
  if (MODE >= 1) {
    int nbn = N / BNg, nbm = M / BMg;
    int idlin = blockIdx.x;
    int nb = idlin % nbn;
    int t2 = idlin / nbn;
    int mb = t2 % nbm;
    int e  = t2 / nbm;
    cnt = counts[e]; off = offs[e];
    if (mb * BMg >= cnt) return;
    Bmat += (size_t)e * (size_t)K * N;
    m0 = mb * BMg; n0 = nb * BNg;
  } else {
    m0 = blockIdx.x * BMg; n0 = blockIdx.y * BNg;
  }
  int tid = threadIdx.x;
  int l = tid & 63, w = tid >> 6;
  int wm = (w >> 1) * 64, wn = (w & 1) * 32;
  int lr = l & 15, kg = l >> 4;

  __shared__ unsigned short Ahs[BMg][PAD];
  __shared__ unsigned short Als[BMg][PAD];
  __shared__ unsigned short Bhs[BNg][PAD];
  __shared__ unsigned short Bls[BNg][PAD];

  f32x4 acc[4][2] = {};

  // A staging: 128 rows x 32 shorts per plane; 256 thr -> 16 shorts (2 us8) each
  int sr = tid >> 1;            // 0..127 (A row)
  int sc = (tid & 1) * 16;      // A k offset (0|16)
  // B staging NT: 64 n-rows x 32 k; thread: n-row = tid>>2, k off = (tid&3)*8
  int nr = tid >> 2, kc = (tid & 3) * 8;
  // B staging TN: 32 k-rows x 64 n; thread: k-row = tid>>3, n off = (tid&7)*8
  int kr = tid >> 3, nc = (tid & 7) * 8;

  int arow;
  if (MODE == 0) arow = m0 + sr;
  else if (MODE == 1) arow = (m0 + sr < cnt) ? elist[off + m0 + sr] : -1;
  else arow = (m0 + sr < cnt) ? (off + m0 + sr) : -1;

  us8 ra[2], rl4[2];
  float4 rb[2];

  auto load_tile = [&](int k0) {
    if (arow >= 0) {
      const unsigned short* ph = Ah + (size_t)arow * K + k0 + sc;
      const unsigned short* pl = Al + (size_t)arow * K + k0 + sc;
      ra[0]  = *(const us8*)(ph);
      ra[1]  = *(const us8*)(ph + 8);
      rl4[0] = *(const us8*)(pl);
      rl4[1] = *(const us8*)(pl + 8);
    } else {
      us8 z = {0, 0, 0, 0, 0, 0, 0, 0};
      ra[0] = z; ra[1] = z; rl4[0] = z; rl4[1] = z;
    }
    const float* pb = (BT == 0)
        ? Bmat + (size_t)(n0 + nr) * K + k0 + kc
        : Bmat + (size_t)(k0 + kr) * N + n0 + nc;
    rb[0] = *(const float4*)(pb);
    rb[1] = *(const float4*)(pb + 4);
  };

  auto store_tile = [&]() {
    *(us8*)&Ahs[sr][sc + 0] = ra[0];
    *(us8*)&Ahs[sr][sc + 8] = ra[1];
    *(us8*)&Als[sr][sc + 0] = rl4[0];
    *(us8*)&Als[sr][sc + 8] = rl4[1];
    if (BT == 0) {
#pragma unroll
      for (int c = 0; c < 2; ++c) {
        float4 v = rb[c];
        us4 h4, l4;
        unsigned short th, tl;
        split2(v.x, th, tl); h4.x = th; l4.x = tl;
        split2(v.y, th, tl); h4.y = th; l4.y = tl;
        split2(v.z, th, tl); h4.z = th; l4.z = tl;
        split2(v.w, th, tl); h4.w = th; l4.w = tl;
        *(us4*)&Bhs[nr][kc + 4 * c] = h4;
        *(us4*)&Bls[nr][kc + 4 * c] = l4;
      }
    } else {
#pragma unroll
      for (int c = 0; c < 2; ++c) {
        float4 v = rb[c];
        unsigned short hh, ll;
        split2(v.x, hh, ll); Bhs[nc + 4 * c + 0][kr] = hh; Bls[nc + 4 * c + 0][kr] = ll;
        split2(v.y, hh, ll); Bhs[nc + 4 * c + 1][kr] = hh; Bls[nc + 4 * c + 1][kr] = ll;
        split2(v.z, hh, ll); Bhs[nc + 4 * c + 2][kr] = hh; Bls[nc + 4 * c + 2][kr] = ll;
        split2(v.w, hh, ll); Bhs[nc + 4 * c + 3][kr] = hh; Bls[nc + 4 * c + 3][kr] = ll;
      }
    }
  };

  load_tile(0);
  for (int k0 = 0; k0 < K; k0 += BKg) {
    store_tile();
    __syncthreads();
    if (k0 + BKg < K) load_tile(k0 + BKg);
    // ---- compute on LDS tile (one 32-wide K slab) ----
    int kk = kg * 8;
    s16x8 bh[2], bl[2];
#pragma unroll
    for (int nf = 0; nf < 2; ++nf) {
      bh[nf] = *(const s16x8*)&Bhs[wn + nf * 16 + lr][kk];
      bl[nf] = *(const s16x8*)&Bls[wn + nf * 16 + lr][kk];
    }
#pragma unroll
    for (int mf = 0; mf < 4; ++mf) {
      s16x8 ah = *(const s16x8*)&Ahs[wm + mf * 16 + lr][kk];
      s16x8 al = *(const s16x8*)&Als[wm + mf * 16 + lr][kk];
#pragma unroll
      for (int nf = 0; nf < 2; ++nf) {
        acc[mf][nf] = __builtin_amdgcn_mfma_f32_16x16x32_bf16(ah, bh[nf], acc[mf][nf], 0, 0, 0);
        acc[mf][nf] = __builtin_amdgcn_mfma_f32_16x16x32_bf16(al, bh[nf], acc[mf][nf], 0, 0, 0);
        acc[mf][nf] = __builtin_amdgcn_mfma_f32_16x16x32_bf16(ah, bl[nf], acc[mf][nf], 0, 0, 0);
      }
    }
    __syncthreads();
  }

  // ---- epilogue ----
  int rbase = (l >> 4) * 4;
#pragma unroll
  for (int mf = 0; mf < 4; ++mf) {
#pragma unroll
    for (int nf = 0; nf < 2; ++nf) {
      int n = n0 + wn + nf * 16 + lr;
#pragma unroll
      for (int j = 0; j < 4; ++j) {
        int rloc = m0 + wm + mf * 16 + rbase + j;
        float v = acc[mf][nf][j];
        if (MODE == 0) {
          if (bias) v += bias[n];
          if (resid) v += resid[(size_t)rloc * N + n];
          C[(size_t)rloc * N + n] = v;
        } else if (MODE == 1) {
          if (rloc < cnt) {
            float g = 0.5f * v * (1.0f + erff(v * 0.70710678118654752f));
            unsigned short hh, ll;
            split2(g, hh, ll);
            size_t p = (size_t)(off + rloc) * N + n;
            Oh[p] = hh; Ol[p] = ll;
          }
        } else {
          if (rloc < cnt) {
            int tok = elist[off + rloc];
            float cf = ecoef[off + rloc];
            atomicAdd(&C[(size_t)tok * N + n], cf * v);
          }
        }
      }
    }
  }
}

// ---------------- tiled flash attention (epilogue -> bf16 hi/lo ctx planes) ----------------
__global__ __launch_bounds__(256) void k_attn_tile(const float* __restrict__ qkv,
                                                   unsigned short* __restrict__ ctx_hi,
                                                   unsigned short* __restrict__ ctx_lo) {
  int qt = blockIdx.x, h = blockIdx.y;
  int q0 = qt * 64;
  int tid = threadIdx.x;
  int tx = tid & 15, ty = tid >> 4;

  __shared__ float Qs[64][68];   // Q^T: [d][q]
  __shared__ float KPs[64][68];  // K^T: [d][j], reused as P^T: [j][q]
  __shared__ float Vs[64][68];   // V:   [j][d]

  float oacc[4][4] = {};
  float m[4] = {-INFINITY, -INFINITY, -INFINITY, -INFINITY};
  float l[4] = {0.f, 0.f, 0.f, 0.f};

  int lrr = tid >> 2;
  int d0 = (tid & 3) * 16;

  {
    const float* qbase = qkv + (size_t)(q0 + lrr) * 3072 + h * 64 + d0;
#pragma unroll
    for (int c = 0; c < 4; ++c) {
      float4 qv = *(const float4*)(qbase + 4 * c);
      Qs[d0 + 4 * c + 0][lrr] = qv.x * 0.125f;
      Qs[d0 + 4 * c + 1][lrr] = qv.y * 0.125f;
      Qs[d0 + 4 * c + 2][lrr] = qv.z * 0.125f;
      Qs[d0 + 4 * c + 3][lrr] = qv.w * 0.125f;
    }
  }
  __syncthreads();

  for (int jt = 0; jt <= qt; ++jt) {
    int j0 = jt * 64;
    {
      const float* kbase = qkv + (size_t)(j0 + lrr) * 3072 + 1024 + h * 64 + d0;
      const float* vbase = qkv + (size_t)(j0 + lrr) * 3072 + 2048 + h * 64 + d0;
#pragma unroll
      for (int c = 0; c < 4; ++c) {
        float4 kv = *(const float4*)(kbase + 4 * c);
        KPs[d0 + 4 * c + 0][lrr] = kv.x;
        KPs[d0 + 4 * c + 1][lrr] = kv.y;
        KPs[d0 + 4 * c + 2][lrr] = kv.z;
        KPs[d0 + 4 * c + 3][lrr] = kv.w;
        *(float4*)&Vs[lrr][d0 + 4 * c] = *(const float4*)(vbase + 4 * c);
      }
    }
    __syncthreads();

    float sacc[4][4] = {};
#pragma unroll 8
    for (int kk = 0; kk < 64; ++kk) {
      float4 a = *(const float4*)&Qs[kk][ty * 4];
      float4 b = *(const float4*)&KPs[kk][tx * 4];
      const float* ap = (const float*)&a;
      const float* bp = (const float*)&b;
#pragma unroll
      for (int i = 0; i < 4; ++i)
#pragma unroll
        for (int jj = 0; jj < 4; ++jj)
          sacc[i][jj] = fmaf(ap[i], bp[jj], sacc[i][jj]);
    }

    if (jt == qt) {
#pragma unroll
      for (int i = 0; i < 4; ++i)
#pragma unroll
        for (int jj = 0; jj < 4; ++jj)
          if (tx * 4 + jj > ty * 4 + i) sacc[i][jj] = -INFINITY;
    }

#pragma unroll
    for (int i = 0; i < 4; ++i) {
      float rm = fmaxf(fmaxf(sacc[i][0], sacc[i][1]),
                       fmaxf(sacc[i][2], sacc[i][3]));
#pragma unroll
      for (int o = 8; o > 0; o >>= 1) rm = fmaxf(rm, __shfl_xor(rm, o, 64));
      float mnew = fmaxf(m[i], rm);
      float alpha = __expf(m[i] - mnew);
      float rs = 0.f;
#pragma unroll
      for (int jj = 0; jj < 4; ++jj) {
        float p = __expf(sacc[i][jj] - mnew);
        sacc[i][jj] = p;
        rs += p;
      }
#pragma unroll
      for (int o = 8; o > 0; o >>= 1) rs += __shfl_xor(rs, o, 64);
      l[i] = l[i] * alpha + rs;
      m[i] = mnew;
#pragma unroll
      for (int jj = 0; jj < 4; ++jj) oacc[i][jj] *= alpha;
    }

    __syncthreads();
#pragma unroll
    for (int i = 0; i < 4; ++i)
#pragma unroll
      for (int jj = 0; jj < 4; ++jj)
        KPs[tx * 4 + jj][ty * 4 + i] = sacc[i][jj];
    __syncthreads();

#pragma unroll 8
    for (int kk = 0; kk < 64; ++kk) {
      float4 a = *(const float4*)&KPs[kk][ty * 4];
      float4 b = *(const float4*)&Vs[kk][tx * 4];
      const float* ap = (const float*)&a;
      const float* bp = (const float*)&b;
#pragma unroll
      for (int i = 0; i < 4; ++i)
#pragma unroll
        for (int jj = 0; jj < 4; ++jj)
          oacc[i][jj] = fmaf(ap[i], bp[jj], oacc[i][jj]);
    }
    __syncthreads();
  }

#pragma unroll
  for (int i = 0; i < 4; ++i) {
    float inv = 1.0f / l[i];
    int mrow = q0 + ty * 4 + i;
    size_t base = (size_t)mrow * Hc + h * 64 + tx * 4;
    us4 hv, lv;
#pragma unroll
    for (int jj = 0; jj < 4; ++jj) {
      float v = oacc[i][jj] * inv;
      unsigned short hh, ll;
      split2(v, hh, ll);
      hv[jj] = hh; lv[jj] = ll;
    }
    *(us4*)&ctx_hi[base] = hv;
    *(us4*)&ctx_lo[base] = lv;
  }
}

// ---------------- router: softmax over 8 experts + top-2 + counts ----------------
__global__ __launch_bounds__(256) void k_router(const float* __restrict__ xf,
    const float* __restrict__ rw, int* __restrict__ topi,
    float* __restrict__ topw, int* __restrict__ counts) {
  int t = blockIdx.x;
  int tid = threadIdx.x;
  int e = tid >> 5, l = tid & 31;
  const float* xr = xf + (size_t)t * Hc;
  const float* we = rw + (size_t)e * Hc;
  float s = 0.f;
  for (int hh = l; hh < Hc; hh += 32) s += xr[hh] * we[hh];
  __shared__ float red[256];
  red[tid] = s; __syncthreads();
  for (int st = 16; st > 0; st >>= 1) {
    if (l < st) red[tid] += red[tid + st];
    __syncthreads();
  }
  if (tid == 0) {
    float lg[Ec], pr[Ec];
    float mx = -INFINITY;
    for (int k = 0; k < Ec; k++) { lg[k] = red[k * 32]; mx = fmaxf(mx, lg[k]); }
    float ps = 0.f;
    for (int k = 0; k < Ec; k++) { pr[k] = expf(lg[k] - mx); ps += pr[k]; }
    float inv = 1.0f / ps;
    for (int k = 0; k < Ec; k++) pr[k] *= inv;
    int i1 = 0;
    for (int k = 1; k < Ec; k++) if (pr[k] > pr[i1]) i1 = k;
    int i2 = (i1 == 0) ? 1 : 0;
    for (int k = 0; k < Ec; k++)
      if (k != i1 && pr[k] > pr[i2]) i2 = k;
    topi[2 * t] = i1; topi[2 * t + 1] = i2;
    topw[2 * t] = pr[i1]; topw[2 * t + 1] = pr[i2];
    atomicAdd(&counts[i1], 1);
    atomicAdd(&counts[i2], 1);
  }
}

__global__ void k_offs(const int* __restrict__ counts, int* __restrict__ offs) {
  int acc = 0;
  for (int e = 0; e < Ec; e++) { offs[e] = acc; acc += counts[e]; }
}

__global__ __launch_bounds__(256) void k_scatter(const int* __restrict__ topi,
    const float* __restrict__ topw, const int* __restrict__ offs,
    int* __restrict__ cursor, int* __restrict__ elist,
    float* __restrict__ ecoef) {
  int t = blockIdx.x * 256 + threadIdx.x;
  if (t >= Sc) return;
#pragma unroll
  for (int s = 0; s < Kc; s++) {
    int e = topi[2 * t + s];
    int p = atomicAdd(&cursor[e], 1);
    int gslot = offs[e] + p;
    elist[gslot] = t;
    ecoef[gslot] = topw[2 * t + s];
  }
}

extern "C" void kernel_launch(void* const* d_in, const int* in_sizes, int n_in,
                              void* d_out, int out_size, void* d_ws, size_t ws_size,
                              hipStream_t stream) {
  const int*   idx   = (const int*)d_in[0];
  const float* tok   = (const float*)d_in[1];
  const float* pos   = (const float*)d_in[2];
  const float* ln1g  = (const float*)d_in[3];
  const float* ln1b  = (const float*)d_in[4];
  const float* wqkv  = (const float*)d_in[5];
  const float* bqkv  = (const float*)d_in[6];
  const float* wo    = (const float*)d_in[7];
  const float* bo    = (const float*)d_in[8];
  const float* ln2g  = (const float*)d_in[9];
  const float* ln2b  = (const float*)d_in[10];
  const float* rw    = (const float*)d_in[11];
  const float* w1    = (const float*)d_in[12];
  const float* w2    = (const float*)d_in[13];
  const float* lnfg  = (const float*)d_in[14];
  const float* lnfb  = (const float*)d_in[15];

  float* ws   = (float*)d_ws;
  float* x    = ws;                    // Sc*Hc
  float* lnb  = x + Sc * Hc;           // Sc*Hc
  float* qkv  = lnb + Sc * Hc;         // Sc*3*Hc
  float* topw  = qkv + Sc * 3 * Hc;    // Sc*Kc
  float* ecoef = topw + Sc * Kc;       // Sc*Kc
  int* topi    = (int*)(ecoef + Sc * Kc);  // Sc*Kc
  int* elist   = topi + Sc * Kc;           // Sc*Kc
  int* counts  = elist + Sc * Kc;          // Ec
  int* cursor  = counts + Ec;              // Ec
  int* offs    = cursor + Ec;              // Ec
  unsigned short* lnb_hi = (unsigned short*)(offs + Ec);   // Sc*Hc ushort
  unsigned short* lnb_lo = lnb_hi + (size_t)Sc * Hc;       // Sc*Hc ushort

  // d_out scratch (262 MB): h1 bf16 planes + ctx bf16 planes; all consumed
  // before the LM head overwrites d_out with logits.
  unsigned short* h1_hi  = (unsigned short*)d_out;                 // Sc*Kc*FFc
  unsigned short* h1_lo  = h1_hi + (size_t)Sc * Kc * FFc;
  unsigned short* ctx_hi = h1_lo + (size_t)Sc * Kc * FFc;          // Sc*Hc
  unsigned short* ctx_lo = ctx_hi + (size_t)Sc * Hc;

  k_embed<<<Sc, 256, 0, stream>>>(idx, tok, pos, x);
  for (int l = 0; l < Lc; l++) {
    k_ln<<<Sc, 256, 0, stream>>>(x, ln1g + l * Hc, ln1b + l * Hc, lnb, lnb_hi, lnb_lo);
    // QKV: [S,3H] = lnb @ wqkv^T + bqkv
    k_mfma_gemm<0, 0><<<dim3(Sc / BMg, 3 * Hc / BNg), 256, 0, stream>>>(
        lnb_hi, lnb_lo, wqkv + (size_t)l * 3 * Hc * Hc, bqkv + l * 3 * Hc,
        nullptr, qkv, nullptr, nullptr, nullptr, nullptr, nullptr, nullptr,
        Sc, 3 * Hc, Hc);
    k_attn_tile<<<dim3(Sc / 64, NHc), 256, 0, stream>>>(qkv, ctx_hi, ctx_lo);
    // WO: x += ctx @ wo^T + bo
    k_mfma_gemm<0, 0><<<dim3(Sc / BMg, Hc / BNg), 256, 0, stream>>>(
        ctx_hi, ctx_lo, wo + (size_t)l * Hc * Hc, bo + l * Hc, x, x,
        nullptr, nullptr, nullptr, nullptr, nullptr, nullptr, Sc, Hc, Hc);
    k_ln<<<Sc, 256, 0, stream>>>(x, ln2g + l * Hc, ln2b + l * Hc, lnb, lnb_hi, lnb_lo);
    hipMemsetAsync(counts, 0, 2 * Ec * sizeof(int), stream);
    k_router<<<Sc, 256, 0, stream>>>(lnb, rw + (size_t)l * Ec * Hc, topi, topw, counts);
    k_offs<<<1, 1, 0, stream>>>(counts, offs);
    k_scatter<<<Sc / 256, 256, 0, stream>>>(topi, topw, offs, cursor, elist, ecoef);
    // MoE GEMM1: h1 = gelu(gather(lnb) @ w1[e]); w1 is [K=H][N=FF]
    // 1D grid, n fastest: spreads active blocks across all 8 XCDs.
    k_mfma_gemm<1, 1><<<(FFc / BNg) * (Sc * Kc / BMg) * Ec, 256, 0, stream>>>(
        lnb_hi, lnb_lo, w1 + (size_t)l * Ec * Hc * FFc, nullptr, nullptr,
        nullptr, h1_hi, h1_lo, elist, nullptr, counts, offs, Sc * Kc, FFc, Hc);
    // MoE GEMM2: x[tok] += coef * (h1 @ w2[e]); w2 is [K=FF][N=H]
    k_mfma_gemm<2, 1><<<(Hc / BNg) * (Sc * Kc / BMg) * Ec, 256, 0, stream>>>(
        h1_hi, h1_lo, w2 + (size_t)l * Ec * FFc * Hc, nullptr, nullptr,
        x, nullptr, nullptr, elist, ecoef, counts, offs, Sc * Kc, Hc, FFc);
  }
  k_ln<<<Sc, 256, 0, stream>>>(x, lnfg, lnfb, lnb, lnb_hi, lnb_lo);
  // LM head: logits = lnb @ tok^T
  k_mfma_gemm<0, 0><<<dim3(Sc / BMg, Vc / BNg), 256, 0, stream>>>(
      lnb_hi, lnb_lo, tok, nullptr, nullptr, (float*)d_out,
      nullptr, nullptr, nullptr, nullptr, nullptr, nullptr, Sc, Vc, Hc);
}